// Round 7
// baseline (871.065 us; speedup 1.0000x reference)
//
#include <hip/hip_runtime.h>

#define DIM 128
#define NEG 0.2f
#define BSZ 512    // dst nodes per CSR bucket (dlow = 9 bits)
#define CB  256    // edge chunks for CSR partition
#define GM  128    // rows per GEMM block

__device__ __forceinline__ float lrelu(float v) { return v > 0.f ? v : NEG * v; }

// ------------- GEMM + fused attention logits: H = X@W, al = H@a_src, ar = H@a_dst
// W staged in LDS (64 KB) -> 2 blocks/CU. 512 threads, 128 rows/block.
__global__ __launch_bounds__(512, 4) void gemm128_fused(const float* __restrict__ X,
                                                        const float* __restrict__ W,
                                                        const float* __restrict__ asrc,
                                                        const float* __restrict__ adst,
                                                        float* __restrict__ H,
                                                        float* __restrict__ al,
                                                        float* __restrict__ ar, int N) {
    __shared__ float sw[128 * 128];  // 64 KB
    const int t = threadIdx.x;
    const int r0g = blockIdx.x * GM;

    {
        float4* sw4 = (float4*)sw;
        const float4* W4 = (const float4*)W;
#pragma unroll
        for (int i = 0; i < 8; ++i) sw4[t + i * 512] = W4[t + i * 512];
    }
    __syncthreads();

    const int c0 = (t & 15) * 8;
    const int rq = (t >> 4) * 4;
    const int row0 = r0g + rq;

    const float* xr[4];
#pragma unroll
    for (int i = 0; i < 4; ++i) {
        int r = row0 + i;
        if (r >= N) r = N - 1;
        xr[i] = X + (size_t)r * DIM;
    }

    float acc[4][8];
#pragma unroll
    for (int i = 0; i < 4; ++i)
#pragma unroll
        for (int j = 0; j < 8; ++j) acc[i][j] = 0.f;

    float4 xc[4];
#pragma unroll
    for (int i = 0; i < 4; ++i) xc[i] = *(const float4*)(xr[i]);

    auto compute = [&](int k, const float4* xv) {
#pragma unroll
        for (int kk = 0; kk < 4; ++kk) {
            const float4 wa = *(const float4*)(sw + (k + kk) * 128 + c0);
            const float4 wb = *(const float4*)(sw + (k + kk) * 128 + c0 + 4);
#pragma unroll
            for (int i = 0; i < 4; ++i) {
                const float xs = (kk == 0) ? xv[i].x : (kk == 1) ? xv[i].y
                                : (kk == 2) ? xv[i].z : xv[i].w;
                acc[i][0] += xs * wa.x; acc[i][1] += xs * wa.y;
                acc[i][2] += xs * wa.z; acc[i][3] += xs * wa.w;
                acc[i][4] += xs * wb.x; acc[i][5] += xs * wb.y;
                acc[i][6] += xs * wb.z; acc[i][7] += xs * wb.w;
            }
        }
    };

    for (int kc = 0; kc < 31; ++kc) {
        const int k = kc * 4;
        float4 xn[4];
#pragma unroll
        for (int i = 0; i < 4; ++i) xn[i] = *(const float4*)(xr[i] + k + 4);
        compute(k, xc);
#pragma unroll
        for (int i = 0; i < 4; ++i) xc[i] = xn[i];
    }
    compute(124, xc);

#pragma unroll
    for (int i = 0; i < 4; ++i) {
        if (row0 + i < N) {
            float* hp = H + (size_t)(row0 + i) * DIM + c0;
            *(float4*)hp = make_float4(acc[i][0], acc[i][1], acc[i][2], acc[i][3]);
            *(float4*)(hp + 4) = make_float4(acc[i][4], acc[i][5], acc[i][6], acc[i][7]);
        }
    }

    const float4 av0 = *(const float4*)(asrc + c0);
    const float4 av1 = *(const float4*)(asrc + c0 + 4);
    const float4 dv0 = *(const float4*)(adst + c0);
    const float4 dv1 = *(const float4*)(adst + c0 + 4);
    float pa[4], pr[4];
#pragma unroll
    for (int i = 0; i < 4; ++i) {
        pa[i] = acc[i][0] * av0.x + acc[i][1] * av0.y + acc[i][2] * av0.z + acc[i][3] * av0.w
              + acc[i][4] * av1.x + acc[i][5] * av1.y + acc[i][6] * av1.z + acc[i][7] * av1.w;
        pr[i] = acc[i][0] * dv0.x + acc[i][1] * dv0.y + acc[i][2] * dv0.z + acc[i][3] * dv0.w
              + acc[i][4] * dv1.x + acc[i][5] * dv1.y + acc[i][6] * dv1.z + acc[i][7] * dv1.w;
    }
#pragma unroll
    for (int off = 8; off; off >>= 1) {
#pragma unroll
        for (int i = 0; i < 4; ++i) {
            pa[i] += __shfl_xor(pa[i], off);
            pr[i] += __shfl_xor(pr[i], off);
        }
    }
    if ((t & 15) == 0) {
#pragma unroll
        for (int i = 0; i < 4; ++i) {
            if (row0 + i < N) {
                al[row0 + i] = pa[i];
                ar[row0 + i] = pr[i];
            }
        }
    }
}

// ================= CSR build: two-level counting sort, zero global atomics ===
__device__ __forceinline__ void edge_decode(int e, const int* ei, const int* eix,
                                            int E1, int N, int E2, int& src, int& d) {
    if (e < E1) {
        src = ei[e];
        d = ei[E1 + e];
    } else {
        int k = e - E1;
        src = eix[k];
        d = N + eix[E2 + k];
    }
}

__global__ __launch_bounds__(256) void csr_hist(const int* __restrict__ ei,
                                                const int* __restrict__ eix,
                                                int* __restrict__ g_hist,
                                                int E1, int E2, int N, int NB, int CE) {
    __shared__ int h[256];
    const int t = threadIdx.x;
    const int c = blockIdx.x;
    h[t] = 0;
    __syncthreads();
    const int Etot = E1 + E2;
    const int beg = c * CE;
    const int end = min(Etot, beg + CE);
    for (int e = beg + t; e < end; e += 256) {
        int src, d;
        edge_decode(e, ei, eix, E1, N, E2, src, d);
        atomicAdd(&h[d >> 9], 1);
    }
    __syncthreads();
    if (t < NB) g_hist[t * CB + c] = h[t];
}

__global__ __launch_bounds__(1024) void bsum_kernel(const int* __restrict__ in,
                                                    int* __restrict__ bsum, int L) {
    __shared__ int wsum[16];
    int t = threadIdx.x, wave = t >> 6, lane = t & 63;
    int i = blockIdx.x * 1024 + t;
    int v = (i < L) ? in[i] : 0;
#pragma unroll
    for (int off = 32; off; off >>= 1) v += __shfl_xor(v, off);
    if (lane == 0) wsum[wave] = v;
    __syncthreads();
    if (t == 0) {
        int s = 0;
#pragma unroll
        for (int j = 0; j < 16; ++j) s += wsum[j];
        bsum[blockIdx.x] = s;
    }
}

__global__ __launch_bounds__(128) void scan_small(int* __restrict__ bsum, int nb) {
    __shared__ int w0tot;
    int t = threadIdx.x;
    int v = (t < nb) ? bsum[t] : 0;
    int s = v;
#pragma unroll
    for (int off = 1; off < 64; off <<= 1) {
        int u = __shfl_up(s, off);
        if ((t & 63) >= off) s += u;
    }
    if (t == 63) w0tot = s;
    __syncthreads();
    if (t >= 64) s += w0tot;
    if (t < nb) bsum[t] = s - v;  // exclusive
}

__global__ __launch_bounds__(1024) void bscan_kernel(const int* __restrict__ in,
                                                     const int* __restrict__ bsum,
                                                     int* __restrict__ out, int L) {
    __shared__ int wsum[16];
    __shared__ int woff[16];
    int t = threadIdx.x, wave = t >> 6, lane = t & 63;
    int i = blockIdx.x * 1024 + t;
    int v = (i < L) ? in[i] : 0;
    int s = v;
#pragma unroll
    for (int off = 1; off < 64; off <<= 1) {
        int u = __shfl_up(s, off);
        if (lane >= off) s += u;
    }
    if (lane == 63) wsum[wave] = s;
    __syncthreads();
    if (t == 0) {
        int r = 0;
#pragma unroll
        for (int j = 0; j < 16; ++j) { woff[j] = r; r += wsum[j]; }
    }
    __syncthreads();
    if (i < L) out[i] = bsum[blockIdx.x] + woff[wave] + s - v;
}

__global__ __launch_bounds__(256) void csr_partition(const int* __restrict__ ei,
                                                     const int* __restrict__ eix,
                                                     const int* __restrict__ g_base,
                                                     unsigned* __restrict__ staging,
                                                     int E1, int E2, int N, int NB, int CE) {
    __shared__ int cur[256];
    const int t = threadIdx.x;
    const int c = blockIdx.x;
    if (t < NB) cur[t] = g_base[t * CB + c];
    __syncthreads();
    const int Etot = E1 + E2;
    const int beg = c * CE;
    const int end = min(Etot, beg + CE);
    for (int e = beg + t; e < end; e += 256) {
        int src, d;
        edge_decode(e, ei, eix, E1, N, E2, src, d);
        int p = atomicAdd(&cur[d >> 9], 1);
        staging[p] = ((unsigned)(d & (BSZ - 1)) << 22) | (unsigned)src;
    }
}

__global__ __launch_bounds__(256) void csr_finalize(const unsigned* __restrict__ staging,
                                                    const int* __restrict__ g_base,
                                                    int* __restrict__ row_off,
                                                    int* __restrict__ col,
                                                    int Ntot, int Etot, int NB) {
    __shared__ int cnt_s[BSZ];
    __shared__ int cur_s[BSZ];
    __shared__ int wsum[4], woff[4];
    const int t = threadIdx.x;
    const int k = blockIdx.x;
    cnt_s[t] = 0;
    cnt_s[t + 256] = 0;
    __syncthreads();
    const int seg_beg = g_base[k * CB];
    const int seg_end = (k == NB - 1) ? Etot : g_base[(k + 1) * CB];
    for (int i = seg_beg + t; i < seg_end; i += 256)
        atomicAdd(&cnt_s[staging[i] >> 22], 1);
    __syncthreads();

    const int a = cnt_s[2 * t], b = cnt_s[2 * t + 1];
    const int tsum = a + b;
    int s = tsum;
    const int lane = t & 63, wv = t >> 6;
#pragma unroll
    for (int off = 1; off < 64; off <<= 1) {
        int u = __shfl_up(s, off);
        if (lane >= off) s += u;
    }
    if (lane == 63) wsum[wv] = s;
    __syncthreads();
    if (t == 0) {
        int r = 0;
#pragma unroll
        for (int j = 0; j < 4; ++j) { woff[j] = r; r += wsum[j]; }
    }
    __syncthreads();
    const int excl = woff[wv] + s - tsum;
    cur_s[2 * t] = seg_beg + excl;
    cur_s[2 * t + 1] = seg_beg + excl + a;
    const int nbase = k * BSZ;
    if (nbase + 2 * t < Ntot)     row_off[nbase + 2 * t]     = seg_beg + excl;
    if (nbase + 2 * t + 1 < Ntot) row_off[nbase + 2 * t + 1] = seg_beg + excl + a;
    __syncthreads();
    for (int i = seg_beg + t; i < seg_end; i += 256) {
        unsigned v = staging[i];
        int p = atomicAdd(&cur_s[v >> 22], 1);
        col[p] = (int)(v & 0x3FFFFFu);
    }
    if (k == 0 && t == 0) row_off[Ntot] = Etot;
}

// ---------------- softmax factored out: per-edge alpha + per-node self-alpha ---
// One wave per node. al (200 KB) is L2-resident -> gathers are cheap.
__global__ __launch_bounds__(256) void alpha_kernel(const float* __restrict__ al,
                                                    const float* __restrict__ ar,
                                                    const int* __restrict__ row_off,
                                                    const int* __restrict__ col,
                                                    float* __restrict__ alpha,
                                                    float* __restrict__ aself, int N) {
    const int w = blockIdx.x * 4 + (threadIdx.x >> 6);
    const int lane = threadIdx.x & 63;
    if (w >= N) return;

    const int beg = row_off[w];
    const int deg = row_off[w + 1] - beg;
    const float arn = ar[w];
    const float vself = lrelu(al[w] + arn);

    float mm = -1e30f, ss = 0.f;
    float v0 = 0.f;                       // cache first-round logit (deg<64 a.s.)
    for (int i = lane; i < deg; i += 64) {
        float v = lrelu(al[col[beg + i]] + arn);
        if (i == lane) v0 = v;
        float nm = fmaxf(mm, v);
        ss = ss * __expf(mm - nm) + __expf(v - nm);
        mm = nm;
    }
#pragma unroll
    for (int off = 32; off; off >>= 1) {
        float mo = __shfl_xor(mm, off);
        float so = __shfl_xor(ss, off);
        float nm = fmaxf(mm, mo);
        ss = ss * __expf(mm - nm) + so * __expf(mo - nm);
        mm = nm;
    }
    {
        float nm = fmaxf(mm, vself);
        ss = ss * __expf(mm - nm) + __expf(vself - nm);
        mm = nm;
    }
    const float m = mm;
    const float invs = 1.f / ss;

    for (int i = lane; i < deg; i += 64) {
        float v = (i == lane) ? v0 : lrelu(al[col[beg + i]] + arn);  // reload is L1/L2-hot
        alpha[beg + i] = __expf(v - m) * invs;
    }
    if (lane == 0) aself[w] = __expf(vself - m) * invs;
}

// ---------------- XCD-sliced weighted gather ------------------------------
// blockIdx%8 = feature slice (16 dims) -> pins each H slice (3.2 MB) to one
// XCD's L2. 16 lanes per node, 64 B per edge-read, 4-edge unroll.
__global__ __launch_bounds__(256) void agg_slice(const float* __restrict__ H,
                                                 const float* __restrict__ alpha,
                                                 const float* __restrict__ aself,
                                                 const int* __restrict__ row_off,
                                                 const int* __restrict__ col,
                                                 const float* __restrict__ bias,
                                                 float* __restrict__ out, int N, int relu) {
    const int s = blockIdx.x & 7;
    const int chunk = blockIdx.x >> 3;
    const int t = threadIdx.x;
    const int g = t >> 4;                // node group 0..15
    const int l = t & 15;                // dim lane
    const int n = chunk * 16 + g;
    if (n >= N) return;
    const int dim = s * 16 + l;

    const int beg = row_off[n];
    const int end = row_off[n + 1];
    float acc = aself[n] * H[(size_t)n * DIM + dim];

    int e = beg;
    for (; e + 3 < end; e += 4) {
        const int c0 = col[e], c1 = col[e + 1], c2 = col[e + 2], c3 = col[e + 3];
        const float a0 = alpha[e], a1 = alpha[e + 1], a2 = alpha[e + 2], a3 = alpha[e + 3];
        const float h0 = H[(size_t)c0 * DIM + dim];
        const float h1 = H[(size_t)c1 * DIM + dim];
        const float h2 = H[(size_t)c2 * DIM + dim];
        const float h3 = H[(size_t)c3 * DIM + dim];
        acc += a0 * h0 + a1 * h1 + a2 * h2 + a3 * h3;
    }
    for (; e < end; ++e)
        acc += alpha[e] * H[(size_t)col[e] * DIM + dim];

    float o = acc + bias[dim];
    if (relu) o = fmaxf(o, 0.f);
    out[(size_t)n * DIM + dim] = o;
}

// ---------------- host-side launch ----------------
extern "C" void kernel_launch(void* const* d_in, const int* in_sizes, int n_in,
                              void* d_out, int out_size, void* d_ws, size_t ws_size,
                              hipStream_t stream) {
    const float* x = (const float*)d_in[0];
    const float* W[5];
    const float* asv[5];
    const float* adv[5];
    const float* bv[5];
    for (int i = 0; i < 5; ++i) {
        W[i]   = (const float*)d_in[1 + 4 * i];
        asv[i] = (const float*)d_in[2 + 4 * i];
        adv[i] = (const float*)d_in[3 + 4 * i];
        bv[i]  = (const float*)d_in[4 + 4 * i];
    }
    const int* ei  = (const int*)d_in[21];
    const int* eix = (const int*)d_in[22];
    const int N  = in_sizes[0] / DIM;
    const int E1 = in_sizes[21] / 2;
    const int E2 = in_sizes[22] / 2;
    const int Ntot = 2 * N;
    const int Etot = E1 + E2;
    const int NB = (Ntot + BSZ - 1) / BSZ;       // 196 for N=50000
    const int CE = (Etot + CB - 1) / CB;

    size_t off = 0;
    auto alloc = [&](size_t bytes) {
        void* r = (char*)d_ws + off;
        off += (bytes + 255) & ~(size_t)255;
        return r;
    };
    float* Hbuf   = (float*)alloc((size_t)N * DIM * sizeof(float));
    float* al     = (float*)alloc((size_t)N * sizeof(float));
    float* ar     = (float*)alloc((size_t)N * sizeof(float));
    float* aself  = (float*)alloc((size_t)N * sizeof(float));
    float* alphab = (float*)alloc((size_t)Etot * sizeof(float));
    int* g_hist   = (int*)alloc((size_t)NB * CB * sizeof(int));
    int* g_base   = (int*)alloc((size_t)NB * CB * sizeof(int));
    int* bsum     = (int*)alloc(128 * sizeof(int));
    int* row      = (int*)alloc((size_t)(Ntot + 1) * sizeof(int));
    int* col      = (int*)alloc((size_t)Etot * sizeof(int));
    (void)ws_size;
    unsigned* staging = (unsigned*)Hbuf;  // aliases Hbuf; dead before first gemm

    float* F = (float*)d_out;

    const int L = NB * CB;
    const int nbb = (L + 1023) / 1024;
    csr_hist<<<CB, 256, 0, stream>>>(ei, eix, g_hist, E1, E2, N, NB, CE);
    bsum_kernel<<<nbb, 1024, 0, stream>>>(g_hist, bsum, L);
    scan_small<<<1, 128, 0, stream>>>(bsum, nbb);
    bscan_kernel<<<nbb, 1024, 0, stream>>>(g_hist, bsum, g_base, L);
    csr_partition<<<CB, 256, 0, stream>>>(ei, eix, g_base, staging, E1, E2, N, NB, CE);
    csr_finalize<<<NB, 256, 0, stream>>>(staging, g_base, row, col, Ntot, Etot, NB);

    const int gemm_blocks = (N + GM - 1) / GM;
    const int node_blocks = (N + 3) / 4;
    const int slice_blocks = ((N + 15) / 16) * 8;

    const float* cur_x = x;
    for (int Lyr = 0; Lyr < 5; ++Lyr) {
        gemm128_fused<<<gemm_blocks, 512, 0, stream>>>(cur_x, W[Lyr], asv[Lyr], adv[Lyr],
                                                       Hbuf, al, ar, N);
        const int* ro = row + ((Lyr % 2 == 0) ? 0 : N);
        alpha_kernel<<<node_blocks, 256, 0, stream>>>(al, ar, ro, col, alphab, aself, N);
        agg_slice<<<slice_blocks, 256, 0, stream>>>(Hbuf, alphab, aself, ro, col, bv[Lyr],
                                                    F, N, (Lyr < 4) ? 1 : 0);
        cur_x = F;
    }
}

// Round 8
// 691.976 us; speedup vs baseline: 1.2588x; 1.2588x over previous
//
#include <hip/hip_runtime.h>

#define DIM 128
#define NEG 0.2f
#define CAP 128    // per-node LDS alpha slots in agg
#define BSZ 512    // dst nodes per CSR bucket (dlow = 9 bits)
#define CB  256    // edge chunks for CSR partition

typedef __attribute__((ext_vector_type(8))) short bf16x8;
typedef __attribute__((ext_vector_type(4))) float f32x4;

__device__ __forceinline__ float lrelu(float v) { return v > 0.f ? v : NEG * v; }

__device__ __forceinline__ unsigned short f2bf(float f) {
    unsigned u = __float_as_uint(f);
    unsigned r = (u + 0x7FFFu + ((u >> 16) & 1u)) >> 16;   // RNE
    return (unsigned short)r;
}
__device__ __forceinline__ float bf2f(unsigned short h) {
    return __uint_as_float(((unsigned)h) << 16);
}

// ---------------- split-bf16 conversions ----------------
__global__ __launch_bounds__(256) void convert_x(const float* __restrict__ x,
                                                 unsigned short* __restrict__ hi,
                                                 unsigned short* __restrict__ lo, int n4) {
    int i = blockIdx.x * 256 + threadIdx.x;
    if (i >= n4) return;
    float4 v = ((const float4*)x)[i];
    ushort4 h, l;
    h.x = f2bf(v.x); l.x = f2bf(v.x - bf2f(h.x));
    h.y = f2bf(v.y); l.y = f2bf(v.y - bf2f(h.y));
    h.z = f2bf(v.z); l.z = f2bf(v.z - bf2f(h.z));
    h.w = f2bf(v.w); l.w = f2bf(v.w - bf2f(h.w));
    ((ushort4*)hi)[i] = h;
    ((ushort4*)lo)[i] = l;
}

// transpose + split W -> WT[c][k] (bf16 hi/lo), 128x128
__global__ __launch_bounds__(256) void convert_w(const float* __restrict__ W,
                                                 unsigned short* __restrict__ WThi,
                                                 unsigned short* __restrict__ WTlo) {
    int i = blockIdx.x * 256 + threadIdx.x;   // 16384 total
    if (i >= 16384) return;
    int c = i >> 7, k = i & 127;
    float v = W[k * 128 + c];
    unsigned short h = f2bf(v);
    WThi[i] = h;
    WTlo[i] = f2bf(v - bf2f(h));
}

// ------------- MFMA GEMM + fused attention logits --------------------------
// H = X@W (fp32 out), al = H@a_src, ar = H@a_dst.
// Split-bf16: acc = Xhi*Whi + Xhi*Wlo + Xlo*Whi  (fp32 MFMA accumulate).
// 256 threads = 4 waves; wave handles 16 rows x 128 cols (8 col-tiles).
// Verified layouts: A[m=lane&15][k=(lane>>4)*8+j]; C/D col=lane&15, row=(lane>>4)*4+reg.
__global__ __launch_bounds__(256) void gemm_mfma(const unsigned short* __restrict__ Xhi,
                                                 const unsigned short* __restrict__ Xlo,
                                                 const unsigned short* __restrict__ WThi,
                                                 const unsigned short* __restrict__ WTlo,
                                                 const float* __restrict__ asrc,
                                                 const float* __restrict__ adst,
                                                 float* __restrict__ H,
                                                 float* __restrict__ al,
                                                 float* __restrict__ ar, int N) {
    const int t = threadIdx.x;
    const int wv = t >> 6;
    const int l = t & 63;
    const int r0 = blockIdx.x * 64 + wv * 16;
    const int m = l & 15;          // A-row / C-col within tile
    const int q = l >> 4;          // quad
    int arow = r0 + m;
    if (arow >= N) arow = N - 1;   // clamped load row; stores guarded
    const size_t abase = (size_t)arow * DIM + q * 8;

    f32x4 acc[8];
#pragma unroll
    for (int tt = 0; tt < 8; ++tt) acc[tt] = (f32x4){0.f, 0.f, 0.f, 0.f};

#pragma unroll
    for (int kc = 0; kc < 4; ++kc) {
        const int k0 = kc * 32;
        const bf16x8 ahi = *(const bf16x8*)(Xhi + abase + k0);
        const bf16x8 alo = *(const bf16x8*)(Xlo + abase + k0);
#pragma unroll
        for (int tt = 0; tt < 8; ++tt) {
            const size_t boff = (size_t)(tt * 16 + m) * DIM + k0 + q * 8;
            const bf16x8 bhi = *(const bf16x8*)(WThi + boff);
            const bf16x8 blo = *(const bf16x8*)(WTlo + boff);
            acc[tt] = __builtin_amdgcn_mfma_f32_16x16x32_bf16(ahi, bhi, acc[tt], 0, 0, 0);
            acc[tt] = __builtin_amdgcn_mfma_f32_16x16x32_bf16(ahi, blo, acc[tt], 0, 0, 0);
            acc[tt] = __builtin_amdgcn_mfma_f32_16x16x32_bf16(alo, bhi, acc[tt], 0, 0, 0);
        }
    }

    // store H: lane's reg j -> row r0+q*4+j, col tt*16+m
#pragma unroll
    for (int j = 0; j < 4; ++j) {
        const int rr = r0 + q * 4 + j;
        if (rr < N) {
            float* hp = H + (size_t)rr * DIM + m;
#pragma unroll
            for (int tt = 0; tt < 8; ++tt) hp[tt * 16] = acc[tt][j];
        }
    }

    // fused al/ar epilogue: reduce over C-cols (lanes differing in low 4 bits)
    float pa[4] = {0.f, 0.f, 0.f, 0.f};
    float pr[4] = {0.f, 0.f, 0.f, 0.f};
#pragma unroll
    for (int tt = 0; tt < 8; ++tt) {
        const float as = asrc[tt * 16 + m];
        const float ad = adst[tt * 16 + m];
#pragma unroll
        for (int j = 0; j < 4; ++j) {
            pa[j] += acc[tt][j] * as;
            pr[j] += acc[tt][j] * ad;
        }
    }
#pragma unroll
    for (int off = 8; off; off >>= 1) {
#pragma unroll
        for (int j = 0; j < 4; ++j) {
            pa[j] += __shfl_xor(pa[j], off);
            pr[j] += __shfl_xor(pr[j], off);
        }
    }
    if (m == 0) {
#pragma unroll
        for (int j = 0; j < 4; ++j) {
            const int rr = r0 + q * 4 + j;
            if (rr < N) { al[rr] = pa[j]; ar[rr] = pr[j]; }
        }
    }
}

// ================= CSR build: two-level counting sort, zero global atomics ===
__device__ __forceinline__ void edge_decode(int e, const int* ei, const int* eix,
                                            int E1, int N, int E2, int& src, int& d) {
    if (e < E1) {
        src = ei[e];
        d = ei[E1 + e];
    } else {
        int k = e - E1;
        src = eix[k];
        d = N + eix[E2 + k];
    }
}

__global__ __launch_bounds__(256) void csr_hist(const int* __restrict__ ei,
                                                const int* __restrict__ eix,
                                                int* __restrict__ g_hist,
                                                int E1, int E2, int N, int NB, int CE) {
    __shared__ int h[256];
    const int t = threadIdx.x;
    const int c = blockIdx.x;
    h[t] = 0;
    __syncthreads();
    const int Etot = E1 + E2;
    const int beg = c * CE;
    const int end = min(Etot, beg + CE);
    for (int e = beg + t; e < end; e += 256) {
        int src, d;
        edge_decode(e, ei, eix, E1, N, E2, src, d);
        atomicAdd(&h[d >> 9], 1);
    }
    __syncthreads();
    if (t < NB) g_hist[t * CB + c] = h[t];
}

__global__ __launch_bounds__(1024) void bsum_kernel(const int* __restrict__ in,
                                                    int* __restrict__ bsum, int L) {
    __shared__ int wsum[16];
    int t = threadIdx.x, wave = t >> 6, lane = t & 63;
    int i = blockIdx.x * 1024 + t;
    int v = (i < L) ? in[i] : 0;
#pragma unroll
    for (int off = 32; off; off >>= 1) v += __shfl_xor(v, off);
    if (lane == 0) wsum[wave] = v;
    __syncthreads();
    if (t == 0) {
        int s = 0;
#pragma unroll
        for (int j = 0; j < 16; ++j) s += wsum[j];
        bsum[blockIdx.x] = s;
    }
}

__global__ __launch_bounds__(128) void scan_small(int* __restrict__ bsum, int nb) {
    __shared__ int w0tot;
    int t = threadIdx.x;
    int v = (t < nb) ? bsum[t] : 0;
    int s = v;
#pragma unroll
    for (int off = 1; off < 64; off <<= 1) {
        int u = __shfl_up(s, off);
        if ((t & 63) >= off) s += u;
    }
    if (t == 63) w0tot = s;
    __syncthreads();
    if (t >= 64) s += w0tot;
    if (t < nb) bsum[t] = s - v;  // exclusive
}

__global__ __launch_bounds__(1024) void bscan_kernel(const int* __restrict__ in,
                                                     const int* __restrict__ bsum,
                                                     int* __restrict__ out, int L) {
    __shared__ int wsum[16];
    __shared__ int woff[16];
    int t = threadIdx.x, wave = t >> 6, lane = t & 63;
    int i = blockIdx.x * 1024 + t;
    int v = (i < L) ? in[i] : 0;
    int s = v;
#pragma unroll
    for (int off = 1; off < 64; off <<= 1) {
        int u = __shfl_up(s, off);
        if (lane >= off) s += u;
    }
    if (lane == 63) wsum[wave] = s;
    __syncthreads();
    if (t == 0) {
        int r = 0;
#pragma unroll
        for (int j = 0; j < 16; ++j) { woff[j] = r; r += wsum[j]; }
    }
    __syncthreads();
    if (i < L) out[i] = bsum[blockIdx.x] + woff[wave] + s - v;
}

__global__ __launch_bounds__(256) void csr_partition(const int* __restrict__ ei,
                                                     const int* __restrict__ eix,
                                                     const int* __restrict__ g_base,
                                                     unsigned* __restrict__ staging,
                                                     int E1, int E2, int N, int NB, int CE) {
    __shared__ int cur[256];
    const int t = threadIdx.x;
    const int c = blockIdx.x;
    if (t < NB) cur[t] = g_base[t * CB + c];
    __syncthreads();
    const int Etot = E1 + E2;
    const int beg = c * CE;
    const int end = min(Etot, beg + CE);
    for (int e = beg + t; e < end; e += 256) {
        int src, d;
        edge_decode(e, ei, eix, E1, N, E2, src, d);
        int p = atomicAdd(&cur[d >> 9], 1);
        staging[p] = ((unsigned)(d & (BSZ - 1)) << 22) | (unsigned)src;
    }
}

__global__ __launch_bounds__(256) void csr_finalize(const unsigned* __restrict__ staging,
                                                    const int* __restrict__ g_base,
                                                    int* __restrict__ row_off,
                                                    int* __restrict__ col,
                                                    int Ntot, int Etot, int NB) {
    __shared__ int cnt_s[BSZ];
    __shared__ int cur_s[BSZ];
    __shared__ int wsum[4], woff[4];
    const int t = threadIdx.x;
    const int k = blockIdx.x;
    cnt_s[t] = 0;
    cnt_s[t + 256] = 0;
    __syncthreads();
    const int seg_beg = g_base[k * CB];
    const int seg_end = (k == NB - 1) ? Etot : g_base[(k + 1) * CB];
    for (int i = seg_beg + t; i < seg_end; i += 256)
        atomicAdd(&cnt_s[staging[i] >> 22], 1);
    __syncthreads();

    const int a = cnt_s[2 * t], b = cnt_s[2 * t + 1];
    const int tsum = a + b;
    int s = tsum;
    const int lane = t & 63, wv = t >> 6;
#pragma unroll
    for (int off = 1; off < 64; off <<= 1) {
        int u = __shfl_up(s, off);
        if (lane >= off) s += u;
    }
    if (lane == 63) wsum[wv] = s;
    __syncthreads();
    if (t == 0) {
        int r = 0;
#pragma unroll
        for (int j = 0; j < 4; ++j) { woff[j] = r; r += wsum[j]; }
    }
    __syncthreads();
    const int excl = woff[wv] + s - tsum;
    cur_s[2 * t] = seg_beg + excl;
    cur_s[2 * t + 1] = seg_beg + excl + a;
    const int nbase = k * BSZ;
    if (nbase + 2 * t < Ntot)     row_off[nbase + 2 * t]     = seg_beg + excl;
    if (nbase + 2 * t + 1 < Ntot) row_off[nbase + 2 * t + 1] = seg_beg + excl + a;
    __syncthreads();
    for (int i = seg_beg + t; i < seg_end; i += 256) {
        unsigned v = staging[i];
        int p = atomicAdd(&cur_s[v >> 22], 1);
        col[p] = (int)(v & 0x3FFFFFu);
    }
    if (k == 0 && t == 0) row_off[Ntot] = Etot;
}

// ---------------- fused softmax-by-dst + aggregation (R4 structure) --------
// last=0: relu + write split-bf16 (outHi/outLo). last=1: no relu + fp32 outF.
__global__ __launch_bounds__(256) void agg_kernel(const float* __restrict__ H,
                                                  const float* __restrict__ al,
                                                  const float* __restrict__ ar,
                                                  const int* __restrict__ row_off,
                                                  const int* __restrict__ col,
                                                  const float* __restrict__ bias,
                                                  float* __restrict__ outF,
                                                  unsigned short* __restrict__ outHi,
                                                  unsigned short* __restrict__ outLo,
                                                  int N, int last) {
    __shared__ float salpha[4][CAP];
    const int wv = threadIdx.x >> 6;
    const int w = blockIdx.x * 4 + wv;
    const int lane = threadIdx.x & 63;
    if (w >= N) return;

    const int beg = row_off[w];
    const int deg = row_off[w + 1] - beg;
    const float arn = ar[w];
    const float vself = lrelu(al[w] + arn);

    // phase A: online segment softmax, logits -> LDS
    float mm = -1e30f, ss = 0.f;
    for (int i = lane; i < deg; i += 64) {
        float v = lrelu(al[col[beg + i]] + arn);
        if (i < CAP) salpha[wv][i] = v;
        float nm = fmaxf(mm, v);
        ss = ss * __expf(mm - nm) + __expf(v - nm);
        mm = nm;
    }
#pragma unroll
    for (int off = 32; off; off >>= 1) {
        float mo = __shfl_xor(mm, off);
        float so = __shfl_xor(ss, off);
        float nm = fmaxf(mm, mo);
        ss = ss * __expf(mm - nm) + so * __expf(mo - nm);
        mm = nm;
    }
    {
        float nm = fmaxf(mm, vself);
        ss = ss * __expf(mm - nm) + __expf(vself - nm);
        mm = nm;
    }
    const float m = mm;
    const float invs = 1.f / ss;

    const int capdeg = deg < CAP ? deg : CAP;
    for (int i = lane; i < capdeg; i += 64)
        salpha[wv][i] = __expf(salpha[wv][i] - m) * invs;

    // phase B: weighted aggregation, 2 half-waves x unroll 4
    const int half = lane >> 5;
    const int l32 = lane & 31;
    const float aself = __expf(vself - m) * invs;
    const float4 hs = *(const float4*)(H + (size_t)w * DIM + 4 * l32);
    float4 acc = make_float4(0.f, 0.f, 0.f, 0.f);
    if (half == 0) {
        acc.x = aself * hs.x; acc.y = aself * hs.y;
        acc.z = aself * hs.z; acc.w = aself * hs.w;
    }

    int i = half;
    for (; i + 6 < deg; i += 8) {
        const int e = beg + i;
        int sn0 = col[e], sn1 = col[e + 2], sn2 = col[e + 4], sn3 = col[e + 6];
        float a0, a1, a2, a3;
        if (i + 6 < CAP) {
            a0 = salpha[wv][i];     a1 = salpha[wv][i + 2];
            a2 = salpha[wv][i + 4]; a3 = salpha[wv][i + 6];
        } else {
            a0 = __expf(lrelu(al[sn0] + arn) - m) * invs;
            a1 = __expf(lrelu(al[sn1] + arn) - m) * invs;
            a2 = __expf(lrelu(al[sn2] + arn) - m) * invs;
            a3 = __expf(lrelu(al[sn3] + arn) - m) * invs;
        }
        const float4 h0 = *(const float4*)(H + (size_t)sn0 * DIM + 4 * l32);
        const float4 h1 = *(const float4*)(H + (size_t)sn1 * DIM + 4 * l32);
        const float4 h2 = *(const float4*)(H + (size_t)sn2 * DIM + 4 * l32);
        const float4 h3 = *(const float4*)(H + (size_t)sn3 * DIM + 4 * l32);
        acc.x += a0 * h0.x + a1 * h1.x + a2 * h2.x + a3 * h3.x;
        acc.y += a0 * h0.y + a1 * h1.y + a2 * h2.y + a3 * h3.y;
        acc.z += a0 * h0.z + a1 * h1.z + a2 * h2.z + a3 * h3.z;
        acc.w += a0 * h0.w + a1 * h1.w + a2 * h2.w + a3 * h3.w;
    }
    for (; i < deg; i += 2) {
        int sn = col[beg + i];
        float a = (i < CAP) ? salpha[wv][i]
                            : __expf(lrelu(al[sn] + arn) - m) * invs;
        const float4 hv = *(const float4*)(H + (size_t)sn * DIM + 4 * l32);
        acc.x += a * hv.x; acc.y += a * hv.y;
        acc.z += a * hv.z; acc.w += a * hv.w;
    }

    acc.x += __shfl_xor(acc.x, 32);
    acc.y += __shfl_xor(acc.y, 32);
    acc.z += __shfl_xor(acc.z, 32);
    acc.w += __shfl_xor(acc.w, 32);

    if (half == 0) {
        const float4 b = *(const float4*)(bias + 4 * l32);
        float4 o = make_float4(acc.x + b.x, acc.y + b.y, acc.z + b.z, acc.w + b.w);
        if (last) {
            *(float4*)(outF + (size_t)w * DIM + 4 * l32) = o;
        } else {
            o.x = fmaxf(o.x, 0.f); o.y = fmaxf(o.y, 0.f);
            o.z = fmaxf(o.z, 0.f); o.w = fmaxf(o.w, 0.f);
            ushort4 h, l;
            h.x = f2bf(o.x); l.x = f2bf(o.x - bf2f(h.x));
            h.y = f2bf(o.y); l.y = f2bf(o.y - bf2f(h.y));
            h.z = f2bf(o.z); l.z = f2bf(o.z - bf2f(h.z));
            h.w = f2bf(o.w); l.w = f2bf(o.w - bf2f(h.w));
            *(ushort4*)(outHi + (size_t)w * DIM + 4 * l32) = h;
            *(ushort4*)(outLo + (size_t)w * DIM + 4 * l32) = l;
        }
    }
}

// ---------------- host-side launch ----------------
extern "C" void kernel_launch(void* const* d_in, const int* in_sizes, int n_in,
                              void* d_out, int out_size, void* d_ws, size_t ws_size,
                              hipStream_t stream) {
    const float* x = (const float*)d_in[0];
    const float* W[5];
    const float* asv[5];
    const float* adv[5];
    const float* bv[5];
    for (int i = 0; i < 5; ++i) {
        W[i]   = (const float*)d_in[1 + 4 * i];
        asv[i] = (const float*)d_in[2 + 4 * i];
        adv[i] = (const float*)d_in[3 + 4 * i];
        bv[i]  = (const float*)d_in[4 + 4 * i];
    }
    const int* ei  = (const int*)d_in[21];
    const int* eix = (const int*)d_in[22];
    const int N  = in_sizes[0] / DIM;
    const int E1 = in_sizes[21] / 2;
    const int E2 = in_sizes[22] / 2;
    const int Ntot = 2 * N;
    const int Etot = E1 + E2;
    const int NB = (Ntot + BSZ - 1) / BSZ;       // 196 for N=50000
    const int CE = (Etot + CB - 1) / CB;

    size_t off = 0;
    auto alloc = [&](size_t bytes) {
        void* r = (char*)d_ws + off;
        off += (bytes + 255) & ~(size_t)255;
        return r;
    };
    float* Hbuf  = (float*)alloc((size_t)N * DIM * sizeof(float));
    unsigned short* Xhi = (unsigned short*)alloc((size_t)N * DIM * 2);
    unsigned short* Xlo = (unsigned short*)alloc((size_t)N * DIM * 2);
    float* al    = (float*)alloc((size_t)N * sizeof(float));
    float* ar    = (float*)alloc((size_t)N * sizeof(float));
    unsigned short* wthi = (unsigned short*)alloc(5 * 16384 * 2);
    unsigned short* wtlo = (unsigned short*)alloc(5 * 16384 * 2);
    int* g_hist  = (int*)alloc((size_t)NB * CB * sizeof(int));
    int* g_base  = (int*)alloc((size_t)NB * CB * sizeof(int));
    int* bsum    = (int*)alloc(128 * sizeof(int));
    int* row     = (int*)alloc((size_t)(Ntot + 1) * sizeof(int));
    int* col     = (int*)alloc((size_t)Etot * sizeof(int));
    (void)ws_size;
    unsigned* staging = (unsigned*)Hbuf;  // aliases Hbuf; dead before first gemm

    float* F = (float*)d_out;

    // ---- conversions (x once; W per layer, transposed+split) ----
    const int n4 = N * DIM / 4;
    convert_x<<<(n4 + 255) / 256, 256, 0, stream>>>(x, Xhi, Xlo, n4);
    for (int Lyr = 0; Lyr < 5; ++Lyr)
        convert_w<<<64, 256, 0, stream>>>(W[Lyr], wthi + Lyr * 16384, wtlo + Lyr * 16384);

    // ---- CSR build (combined 2N-node graph), no global atomics ----
    const int L = NB * CB;
    const int nbb = (L + 1023) / 1024;
    csr_hist<<<CB, 256, 0, stream>>>(ei, eix, g_hist, E1, E2, N, NB, CE);
    bsum_kernel<<<nbb, 1024, 0, stream>>>(g_hist, bsum, L);
    scan_small<<<1, 128, 0, stream>>>(bsum, nbb);
    bscan_kernel<<<nbb, 1024, 0, stream>>>(g_hist, bsum, g_base, L);
    csr_partition<<<CB, 256, 0, stream>>>(ei, eix, g_base, staging, E1, E2, N, NB, CE);
    csr_finalize<<<NB, 256, 0, stream>>>(staging, g_base, row, col, Ntot, Etot, NB);

    const int gemm_blocks = (N + 63) / 64;
    const int node_blocks = (N + 3) / 4;

    for (int Lyr = 0; Lyr < 5; ++Lyr) {
        gemm_mfma<<<gemm_blocks, 256, 0, stream>>>(Xhi, Xlo,
                                                   wthi + Lyr * 16384, wtlo + Lyr * 16384,
                                                   asv[Lyr], adv[Lyr], Hbuf, al, ar, N);
        const int* ro = row + ((Lyr % 2 == 0) ? 0 : N);
        agg_kernel<<<node_blocks, 256, 0, stream>>>(Hbuf, al, ar, ro, col, bv[Lyr],
                                                    F, Xhi, Xlo, N, (Lyr == 4) ? 1 : 0);
    }
}

// Round 9
// 593.038 us; speedup vs baseline: 1.4688x; 1.1668x over previous
//
#include <hip/hip_runtime.h>

#define DIM 128
#define NEG 0.2f
#define CAP 128    // per-node LDS alpha slots in agg
#define BSZ 512    // dst nodes per CSR bucket (dlow = 9 bits)
#define CB  256    // edge chunks for CSR partition

typedef __attribute__((ext_vector_type(8))) short bf16x8;
typedef __attribute__((ext_vector_type(4))) float f32x4;

__device__ __forceinline__ float lrelu(float v) { return v > 0.f ? v : NEG * v; }

__device__ __forceinline__ unsigned short f2bf(float f) {
    unsigned u = __float_as_uint(f);
    unsigned r = (u + 0x7FFFu + ((u >> 16) & 1u)) >> 16;   // RNE
    return (unsigned short)r;
}
__device__ __forceinline__ float bf2f(unsigned short h) {
    return __uint_as_float(((unsigned)h) << 16);
}

// Packed fragment layout (A and B identical):
//   offset(tile,kc,q,rr,j) = tile*2048 + kc*512 + q*128 + rr*8 + j   (shorts)
// so a wave's 16B fragment for (tile,kc) sits at base + lane*8 shorts.

// ---------------- split-bf16 conversions (write PACKED) ----------------
__global__ __launch_bounds__(256) void convert_x(const float* __restrict__ x,
                                                 unsigned short* __restrict__ hi,
                                                 unsigned short* __restrict__ lo, int n4) {
    int i = blockIdx.x * 256 + threadIdx.x;
    if (i >= n4) return;
    const int p = i * 4;
    const int tile = p >> 11, kc = (p >> 9) & 3, q = (p >> 7) & 3;
    const int rr = (p >> 3) & 15, j0 = p & 7;
    const int row = tile * 16 + rr;
    const int k = kc * 32 + q * 8 + j0;
    float4 v = *(const float4*)(x + (size_t)row * DIM + k);
    ushort4 h, l;
    h.x = f2bf(v.x); l.x = f2bf(v.x - bf2f(h.x));
    h.y = f2bf(v.y); l.y = f2bf(v.y - bf2f(h.y));
    h.z = f2bf(v.z); l.z = f2bf(v.z - bf2f(h.z));
    h.w = f2bf(v.w); l.w = f2bf(v.w - bf2f(h.w));
    *(ushort4*)(hi + p) = h;
    *(ushort4*)(lo + p) = l;
}

// W -> packed B-fragments (B[k][n] = W[k][n]), split hi/lo
__global__ __launch_bounds__(256) void convert_w(const float* __restrict__ W,
                                                 unsigned short* __restrict__ Bhi,
                                                 unsigned short* __restrict__ Blo) {
    int i = blockIdx.x * 256 + threadIdx.x;   // 16384 total
    if (i >= 16384) return;
    const int tt = i >> 11, kc = (i >> 9) & 3, q = (i >> 7) & 3;
    const int n = (i >> 3) & 15, j = i & 7;
    const int c = tt * 16 + n;
    const int k = kc * 32 + q * 8 + j;
    float v = W[k * 128 + c];
    unsigned short h = f2bf(v);
    Bhi[i] = h;
    Blo[i] = f2bf(v - bf2f(h));
}

// ------------- MFMA GEMM + fused attention logits --------------------------
// All fragment loads are wave-contiguous (base + lane*16B). 4 waves/block,
// wave = 16 rows x 128 cols. acc = Xhi*Whi + Xhi*Wlo + Xlo*Whi (fp32 acc).
__global__ __launch_bounds__(256) void gemm_mfma(const unsigned short* __restrict__ Ahi,
                                                 const unsigned short* __restrict__ Alo,
                                                 const unsigned short* __restrict__ Bhi,
                                                 const unsigned short* __restrict__ Blo,
                                                 const float* __restrict__ asrc,
                                                 const float* __restrict__ adst,
                                                 float* __restrict__ H,
                                                 float* __restrict__ al,
                                                 float* __restrict__ ar, int N) {
    const int t = threadIdx.x;
    const int wv = t >> 6;
    const int l = t & 63;
    const int tile = blockIdx.x * 4 + wv;
    const int r0 = tile * 16;
    const int m = l & 15;          // C-col within tile
    const int q = l >> 4;          // quad

    f32x4 acc[8];
#pragma unroll
    for (int tt = 0; tt < 8; ++tt) acc[tt] = (f32x4){0.f, 0.f, 0.f, 0.f};

    const size_t abase = (size_t)tile * 2048 + (size_t)l * 8;
#pragma unroll
    for (int kc = 0; kc < 4; ++kc) {
        const bf16x8 ahi = *(const bf16x8*)(Ahi + abase + kc * 512);
        const bf16x8 alo = *(const bf16x8*)(Alo + abase + kc * 512);
#pragma unroll
        for (int tt = 0; tt < 8; ++tt) {
            const size_t boff = (size_t)tt * 2048 + kc * 512 + (size_t)l * 8;
            const bf16x8 bhi = *(const bf16x8*)(Bhi + boff);
            const bf16x8 blo = *(const bf16x8*)(Blo + boff);
            acc[tt] = __builtin_amdgcn_mfma_f32_16x16x32_bf16(ahi, bhi, acc[tt], 0, 0, 0);
            acc[tt] = __builtin_amdgcn_mfma_f32_16x16x32_bf16(ahi, blo, acc[tt], 0, 0, 0);
            acc[tt] = __builtin_amdgcn_mfma_f32_16x16x32_bf16(alo, bhi, acc[tt], 0, 0, 0);
        }
    }

    // store H: lane's reg j -> row r0+q*4+j, col tt*16+m (16 contiguous dwords/instr)
#pragma unroll
    for (int j = 0; j < 4; ++j) {
        const int rr = r0 + q * 4 + j;
        if (rr < N) {
            float* hp = H + (size_t)rr * DIM + m;
#pragma unroll
            for (int tt = 0; tt < 8; ++tt) hp[tt * 16] = acc[tt][j];
        }
    }

    // fused al/ar epilogue: reduce over C-cols (lanes differing in low 4 bits)
    float pa[4] = {0.f, 0.f, 0.f, 0.f};
    float pr[4] = {0.f, 0.f, 0.f, 0.f};
#pragma unroll
    for (int tt = 0; tt < 8; ++tt) {
        const float as = asrc[tt * 16 + m];
        const float ad = adst[tt * 16 + m];
#pragma unroll
        for (int j = 0; j < 4; ++j) {
            pa[j] += acc[tt][j] * as;
            pr[j] += acc[tt][j] * ad;
        }
    }
#pragma unroll
    for (int off = 8; off; off >>= 1) {
#pragma unroll
        for (int j = 0; j < 4; ++j) {
            pa[j] += __shfl_xor(pa[j], off);
            pr[j] += __shfl_xor(pr[j], off);
        }
    }
    if (m == 0) {
#pragma unroll
        for (int j = 0; j < 4; ++j) {
            const int rr = r0 + q * 4 + j;
            if (rr < N) { al[rr] = pa[j]; ar[rr] = pr[j]; }
        }
    }
}

// ================= CSR build: two-level counting sort, zero global atomics ===
__device__ __forceinline__ void edge_decode(int e, const int* ei, const int* eix,
                                            int E1, int N, int E2, int& src, int& d) {
    if (e < E1) {
        src = ei[e];
        d = ei[E1 + e];
    } else {
        int k = e - E1;
        src = eix[k];
        d = N + eix[E2 + k];
    }
}

__global__ __launch_bounds__(256) void csr_hist(const int* __restrict__ ei,
                                                const int* __restrict__ eix,
                                                int* __restrict__ g_hist,
                                                int E1, int E2, int N, int NB, int CE) {
    __shared__ int h[256];
    const int t = threadIdx.x;
    const int c = blockIdx.x;
    h[t] = 0;
    __syncthreads();
    const int Etot = E1 + E2;
    const int beg = c * CE;
    const int end = min(Etot, beg + CE);
    for (int e = beg + t; e < end; e += 256) {
        int src, d;
        edge_decode(e, ei, eix, E1, N, E2, src, d);
        atomicAdd(&h[d >> 9], 1);
    }
    __syncthreads();
    if (t < NB) g_hist[t * CB + c] = h[t];
}

__global__ __launch_bounds__(1024) void bsum_kernel(const int* __restrict__ in,
                                                    int* __restrict__ bsum, int L) {
    __shared__ int wsum[16];
    int t = threadIdx.x, wave = t >> 6, lane = t & 63;
    int i = blockIdx.x * 1024 + t;
    int v = (i < L) ? in[i] : 0;
#pragma unroll
    for (int off = 32; off; off >>= 1) v += __shfl_xor(v, off);
    if (lane == 0) wsum[wave] = v;
    __syncthreads();
    if (t == 0) {
        int s = 0;
#pragma unroll
        for (int j = 0; j < 16; ++j) s += wsum[j];
        bsum[blockIdx.x] = s;
    }
}

__global__ __launch_bounds__(128) void scan_small(int* __restrict__ bsum, int nb) {
    __shared__ int w0tot;
    int t = threadIdx.x;
    int v = (t < nb) ? bsum[t] : 0;
    int s = v;
#pragma unroll
    for (int off = 1; off < 64; off <<= 1) {
        int u = __shfl_up(s, off);
        if ((t & 63) >= off) s += u;
    }
    if (t == 63) w0tot = s;
    __syncthreads();
    if (t >= 64) s += w0tot;
    if (t < nb) bsum[t] = s - v;  // exclusive
}

__global__ __launch_bounds__(1024) void bscan_kernel(const int* __restrict__ in,
                                                     const int* __restrict__ bsum,
                                                     int* __restrict__ out, int L) {
    __shared__ int wsum[16];
    __shared__ int woff[16];
    int t = threadIdx.x, wave = t >> 6, lane = t & 63;
    int i = blockIdx.x * 1024 + t;
    int v = (i < L) ? in[i] : 0;
    int s = v;
#pragma unroll
    for (int off = 1; off < 64; off <<= 1) {
        int u = __shfl_up(s, off);
        if (lane >= off) s += u;
    }
    if (lane == 63) wsum[wave] = s;
    __syncthreads();
    if (t == 0) {
        int r = 0;
#pragma unroll
        for (int j = 0; j < 16; ++j) { woff[j] = r; r += wsum[j]; }
    }
    __syncthreads();
    if (i < L) out[i] = bsum[blockIdx.x] + woff[wave] + s - v;
}

__global__ __launch_bounds__(256) void csr_partition(const int* __restrict__ ei,
                                                     const int* __restrict__ eix,
                                                     const int* __restrict__ g_base,
                                                     unsigned* __restrict__ staging,
                                                     int E1, int E2, int N, int NB, int CE) {
    __shared__ int cur[256];
    const int t = threadIdx.x;
    const int c = blockIdx.x;
    if (t < NB) cur[t] = g_base[t * CB + c];
    __syncthreads();
    const int Etot = E1 + E2;
    const int beg = c * CE;
    const int end = min(Etot, beg + CE);
    for (int e = beg + t; e < end; e += 256) {
        int src, d;
        edge_decode(e, ei, eix, E1, N, E2, src, d);
        int p = atomicAdd(&cur[d >> 9], 1);
        staging[p] = ((unsigned)(d & (BSZ - 1)) << 22) | (unsigned)src;
    }
}

__global__ __launch_bounds__(256) void csr_finalize(const unsigned* __restrict__ staging,
                                                    const int* __restrict__ g_base,
                                                    int* __restrict__ row_off,
                                                    int* __restrict__ col,
                                                    int Ntot, int Etot, int NB) {
    __shared__ int cnt_s[BSZ];
    __shared__ int cur_s[BSZ];
    __shared__ int wsum[4], woff[4];
    const int t = threadIdx.x;
    const int k = blockIdx.x;
    cnt_s[t] = 0;
    cnt_s[t + 256] = 0;
    __syncthreads();
    const int seg_beg = g_base[k * CB];
    const int seg_end = (k == NB - 1) ? Etot : g_base[(k + 1) * CB];
    for (int i = seg_beg + t; i < seg_end; i += 256)
        atomicAdd(&cnt_s[staging[i] >> 22], 1);
    __syncthreads();

    const int a = cnt_s[2 * t], b = cnt_s[2 * t + 1];
    const int tsum = a + b;
    int s = tsum;
    const int lane = t & 63, wv = t >> 6;
#pragma unroll
    for (int off = 1; off < 64; off <<= 1) {
        int u = __shfl_up(s, off);
        if (lane >= off) s += u;
    }
    if (lane == 63) wsum[wv] = s;
    __syncthreads();
    if (t == 0) {
        int r = 0;
#pragma unroll
        for (int j = 0; j < 4; ++j) { woff[j] = r; r += wsum[j]; }
    }
    __syncthreads();
    const int excl = woff[wv] + s - tsum;
    cur_s[2 * t] = seg_beg + excl;
    cur_s[2 * t + 1] = seg_beg + excl + a;
    const int nbase = k * BSZ;
    if (nbase + 2 * t < Ntot)     row_off[nbase + 2 * t]     = seg_beg + excl;
    if (nbase + 2 * t + 1 < Ntot) row_off[nbase + 2 * t + 1] = seg_beg + excl + a;
    __syncthreads();
    for (int i = seg_beg + t; i < seg_end; i += 256) {
        unsigned v = staging[i];
        int p = atomicAdd(&cur_s[v >> 22], 1);
        col[p] = (int)(v & 0x3FFFFFu);
    }
    if (k == 0 && t == 0) row_off[Ntot] = Etot;
}

// ---------------- fused softmax-by-dst + aggregation (R4 structure) --------
// last=0: relu + write split-bf16 PACKED (for next layer's gemm). last=1: fp32 outF.
__global__ __launch_bounds__(256) void agg_kernel(const float* __restrict__ H,
                                                  const float* __restrict__ al,
                                                  const float* __restrict__ ar,
                                                  const int* __restrict__ row_off,
                                                  const int* __restrict__ col,
                                                  const float* __restrict__ bias,
                                                  float* __restrict__ outF,
                                                  unsigned short* __restrict__ outHi,
                                                  unsigned short* __restrict__ outLo,
                                                  int N, int last) {
    __shared__ float salpha[4][CAP];
    const int wv = threadIdx.x >> 6;
    const int w = blockIdx.x * 4 + wv;
    const int lane = threadIdx.x & 63;
    if (w >= N) return;

    const int beg = row_off[w];
    const int deg = row_off[w + 1] - beg;
    const float arn = ar[w];
    const float vself = lrelu(al[w] + arn);

    // phase A: online segment softmax, logits -> LDS
    float mm = -1e30f, ss = 0.f;
    for (int i = lane; i < deg; i += 64) {
        float v = lrelu(al[col[beg + i]] + arn);
        if (i < CAP) salpha[wv][i] = v;
        float nm = fmaxf(mm, v);
        ss = ss * __expf(mm - nm) + __expf(v - nm);
        mm = nm;
    }
#pragma unroll
    for (int off = 32; off; off >>= 1) {
        float mo = __shfl_xor(mm, off);
        float so = __shfl_xor(ss, off);
        float nm = fmaxf(mm, mo);
        ss = ss * __expf(mm - nm) + so * __expf(mo - nm);
        mm = nm;
    }
    {
        float nm = fmaxf(mm, vself);
        ss = ss * __expf(mm - nm) + __expf(vself - nm);
        mm = nm;
    }
    const float m = mm;
    const float invs = 1.f / ss;

    const int capdeg = deg < CAP ? deg : CAP;
    for (int i = lane; i < capdeg; i += 64)
        salpha[wv][i] = __expf(salpha[wv][i] - m) * invs;

    // phase B: weighted aggregation, 2 half-waves x unroll 4
    const int half = lane >> 5;
    const int l32 = lane & 31;
    const float aself = __expf(vself - m) * invs;
    const float4 hs = *(const float4*)(H + (size_t)w * DIM + 4 * l32);
    float4 acc = make_float4(0.f, 0.f, 0.f, 0.f);
    if (half == 0) {
        acc.x = aself * hs.x; acc.y = aself * hs.y;
        acc.z = aself * hs.z; acc.w = aself * hs.w;
    }

    int i = half;
    for (; i + 6 < deg; i += 8) {
        const int e = beg + i;
        int sn0 = col[e], sn1 = col[e + 2], sn2 = col[e + 4], sn3 = col[e + 6];
        float a0, a1, a2, a3;
        if (i + 6 < CAP) {
            a0 = salpha[wv][i];     a1 = salpha[wv][i + 2];
            a2 = salpha[wv][i + 4]; a3 = salpha[wv][i + 6];
        } else {
            a0 = __expf(lrelu(al[sn0] + arn) - m) * invs;
            a1 = __expf(lrelu(al[sn1] + arn) - m) * invs;
            a2 = __expf(lrelu(al[sn2] + arn) - m) * invs;
            a3 = __expf(lrelu(al[sn3] + arn) - m) * invs;
        }
        const float4 h0 = *(const float4*)(H + (size_t)sn0 * DIM + 4 * l32);
        const float4 h1 = *(const float4*)(H + (size_t)sn1 * DIM + 4 * l32);
        const float4 h2 = *(const float4*)(H + (size_t)sn2 * DIM + 4 * l32);
        const float4 h3 = *(const float4*)(H + (size_t)sn3 * DIM + 4 * l32);
        acc.x += a0 * h0.x + a1 * h1.x + a2 * h2.x + a3 * h3.x;
        acc.y += a0 * h0.y + a1 * h1.y + a2 * h2.y + a3 * h3.y;
        acc.z += a0 * h0.z + a1 * h1.z + a2 * h2.z + a3 * h3.z;
        acc.w += a0 * h0.w + a1 * h1.w + a2 * h2.w + a3 * h3.w;
    }
    for (; i < deg; i += 2) {
        int sn = col[beg + i];
        float a = (i < CAP) ? salpha[wv][i]
                            : __expf(lrelu(al[sn] + arn) - m) * invs;
        const float4 hv = *(const float4*)(H + (size_t)sn * DIM + 4 * l32);
        acc.x += a * hv.x; acc.y += a * hv.y;
        acc.z += a * hv.z; acc.w += a * hv.w;
    }

    acc.x += __shfl_xor(acc.x, 32);
    acc.y += __shfl_xor(acc.y, 32);
    acc.z += __shfl_xor(acc.z, 32);
    acc.w += __shfl_xor(acc.w, 32);

    if (half == 0) {
        const float4 b = *(const float4*)(bias + 4 * l32);
        float4 o = make_float4(acc.x + b.x, acc.y + b.y, acc.z + b.z, acc.w + b.w);
        if (last) {
            *(float4*)(outF + (size_t)w * DIM + 4 * l32) = o;
        } else {
            o.x = fmaxf(o.x, 0.f); o.y = fmaxf(o.y, 0.f);
            o.z = fmaxf(o.z, 0.f); o.w = fmaxf(o.w, 0.f);
            ushort4 h, l;
            h.x = f2bf(o.x); l.x = f2bf(o.x - bf2f(h.x));
            h.y = f2bf(o.y); l.y = f2bf(o.y - bf2f(h.y));
            h.z = f2bf(o.z); l.z = f2bf(o.z - bf2f(h.z));
            h.w = f2bf(o.w); l.w = f2bf(o.w - bf2f(h.w));
            // packed fragment offset for row w, dims d0=4*l32..d0+3
            const int kc = l32 >> 3;
            const int q = (l32 >> 1) & 3;
            const int j0 = (l32 & 1) * 4;
            const size_t p = (size_t)(w >> 4) * 2048 + kc * 512 + q * 128 + (w & 15) * 8 + j0;
            *(ushort4*)(outHi + p) = h;
            *(ushort4*)(outLo + p) = l;
        }
    }
}

// ---------------- host-side launch ----------------
extern "C" void kernel_launch(void* const* d_in, const int* in_sizes, int n_in,
                              void* d_out, int out_size, void* d_ws, size_t ws_size,
                              hipStream_t stream) {
    const float* x = (const float*)d_in[0];
    const float* W[5];
    const float* asv[5];
    const float* adv[5];
    const float* bv[5];
    for (int i = 0; i < 5; ++i) {
        W[i]   = (const float*)d_in[1 + 4 * i];
        asv[i] = (const float*)d_in[2 + 4 * i];
        adv[i] = (const float*)d_in[3 + 4 * i];
        bv[i]  = (const float*)d_in[4 + 4 * i];
    }
    const int* ei  = (const int*)d_in[21];
    const int* eix = (const int*)d_in[22];
    const int N  = in_sizes[0] / DIM;
    const int E1 = in_sizes[21] / 2;
    const int E2 = in_sizes[22] / 2;
    const int Ntot = 2 * N;
    const int Etot = E1 + E2;
    const int NB = (Ntot + BSZ - 1) / BSZ;       // 196 for N=50000
    const int CE = (Etot + CB - 1) / CB;
    const int gemm_blocks = (N + 63) / 64;
    const size_t tiles_alloc = (size_t)gemm_blocks * 4;   // padded tile count

    size_t off = 0;
    auto alloc = [&](size_t bytes) {
        void* r = (char*)d_ws + off;
        off += (bytes + 255) & ~(size_t)255;
        return r;
    };
    float* Hbuf  = (float*)alloc((size_t)N * DIM * sizeof(float));
    unsigned short* Xhi = (unsigned short*)alloc(tiles_alloc * 2048 * 2);
    unsigned short* Xlo = (unsigned short*)alloc(tiles_alloc * 2048 * 2);
    float* al    = (float*)alloc((size_t)N * sizeof(float));
    float* ar    = (float*)alloc((size_t)N * sizeof(float));
    unsigned short* wthi = (unsigned short*)alloc(5 * 16384 * 2);
    unsigned short* wtlo = (unsigned short*)alloc(5 * 16384 * 2);
    int* g_hist  = (int*)alloc((size_t)NB * CB * sizeof(int));
    int* g_base  = (int*)alloc((size_t)NB * CB * sizeof(int));
    int* bsum    = (int*)alloc(128 * sizeof(int));
    int* row     = (int*)alloc((size_t)(Ntot + 1) * sizeof(int));
    int* col     = (int*)alloc((size_t)Etot * sizeof(int));
    (void)ws_size;
    unsigned* staging = (unsigned*)Hbuf;  // aliases Hbuf; dead before first gemm

    float* F = (float*)d_out;

    // ---- conversions (x once; W per layer, packed fragment order) ----
    const int n4 = N * DIM / 4;
    convert_x<<<(n4 + 255) / 256, 256, 0, stream>>>(x, Xhi, Xlo, n4);
    for (int Lyr = 0; Lyr < 5; ++Lyr)
        convert_w<<<64, 256, 0, stream>>>(W[Lyr], wthi + Lyr * 16384, wtlo + Lyr * 16384);

    // ---- CSR build (combined 2N-node graph), no global atomics ----
    const int L = NB * CB;
    const int nbb = (L + 1023) / 1024;
    csr_hist<<<CB, 256, 0, stream>>>(ei, eix, g_hist, E1, E2, N, NB, CE);
    bsum_kernel<<<nbb, 1024, 0, stream>>>(g_hist, bsum, L);
    scan_small<<<1, 128, 0, stream>>>(bsum, nbb);
    bscan_kernel<<<nbb, 1024, 0, stream>>>(g_hist, bsum, g_base, L);
    csr_partition<<<CB, 256, 0, stream>>>(ei, eix, g_base, staging, E1, E2, N, NB, CE);
    csr_finalize<<<NB, 256, 0, stream>>>(staging, g_base, row, col, Ntot, Etot, NB);

    const int node_blocks = (N + 3) / 4;

    for (int Lyr = 0; Lyr < 5; ++Lyr) {
        gemm_mfma<<<gemm_blocks, 256, 0, stream>>>(Xhi, Xlo,
                                                   wthi + Lyr * 16384, wtlo + Lyr * 16384,
                                                   asv[Lyr], adv[Lyr], Hbuf, al, ar, N);
        const int* ro = row + ((Lyr % 2 == 0) ? 0 : N);
        agg_kernel<<<node_blocks, 256, 0, stream>>>(Hbuf, al, ar, ro, col, bv[Lyr],
                                                    F, Xhi, Xlo, N, (Lyr == 4) ? 1 : 0);
    }
}